// Round 9
// baseline (213.015 us; speedup 1.0000x reference)
//
#include <hip/hip_runtime.h>
#include <hip/hip_bf16.h>
#include <math.h>

#define DV 256
#define NSEQ 1024
#define HHEADS 8
#define VV 32000
#define QKSCALE 0.17677669529663687f  // 1/sqrt(32)

typedef __attribute__((ext_vector_type(8))) short short8v;
typedef __attribute__((ext_vector_type(4))) float f32x4;

__device__ __forceinline__ unsigned short f2bf(float f){
  __hip_bfloat16 b = __float2bfloat16(f);
  return *reinterpret_cast<unsigned short*>(&b);
}
__device__ __forceinline__ float bfbits2f(unsigned short u){
  unsigned int x = ((unsigned int)u) << 16;
  return __uint_as_float(x);
}

#define OFF_WQKVP 0
#define OFF_WOT   425984
#define OFF_F1T   557056
#define OFF_F2T   1081344
__global__ __launch_bounds__(256) void transpose_cvt_all(
    const float* __restrict__ Wq, const float* __restrict__ Wk,
    const float* __restrict__ Wv, const float* __restrict__ Wo,
    const float* __restrict__ ppw, const float* __restrict__ f1w,
    const float* __restrict__ f2w, __hip_bfloat16* __restrict__ dst){
  __shared__ float sh[32][33];
  int bid = blockIdx.x;
  int t = threadIdx.x;
  if(bid >= 512 && bid < 528){
    int idx = bid - 512;
    int l = idx >> 3, k0 = (idx & 7) * 32;
    int rowo = t >> 2;
    int kbase = k0 + (t & 3) * 8;
    unsigned short vals[8];
    if(rowo < 8){
      int hh = rowo;
      #pragma unroll
      for(int i=0;i<8;i++) vals[i] = f2bf(ppw[(long)l*2048 + (kbase+i)*HHEADS + hh]);
    } else {
      #pragma unroll
      for(int i=0;i<8;i++) vals[i] = 0;
    }
    unsigned short* d = (unsigned short*)dst + (long)l*212992 + (768+rowo)*256 + kbase;
    #pragma unroll
    for(int i=0;i<8;i++) d[i] = vals[i];
    return;
  }
  const float* src; __hip_bfloat16* d; int K, N, tile;
  if(bid < 384){
    int l = bid / 192, rem = bid % 192, mat = rem >> 6; tile = rem & 63;
    src = (mat==0 ? Wq : (mat==1 ? Wk : Wv)) + l*65536;
    d = dst + (long)l*212992 + mat*65536;
    K = 256; N = 256;
  } else if(bid < 512){
    int b2 = bid - 384; int l = b2 >> 6; tile = b2 & 63;
    src = Wo + l*65536; d = dst + OFF_WOT + l*65536; K = 256; N = 256;
  } else if(bid < 1040){
    int b2 = bid - 528; int l = b2 >> 8; tile = b2 & 255;
    src = f1w + l*262144; d = dst + OFF_F1T + l*262144; K = 256; N = 1024;
  } else {
    int b2 = bid - 1040; int l = b2 >> 8; tile = b2 & 255;
    src = f2w + l*262144; d = dst + OFF_F2T + l*262144; K = 1024; N = 256;
  }
  int ntn = N >> 5;
  int tk = tile / ntn, tn = tile - tk*ntn;
  int k0 = tk*32, n0 = tn*32;
  {
    int rr = t >> 3, cc = (t & 7) * 4;
    float4 v = *(const float4*)&src[(long)(k0+rr)*N + n0 + cc];
    sh[rr][cc]=v.x; sh[rr][cc+1]=v.y; sh[rr][cc+2]=v.z; sh[rr][cc+3]=v.w;
  }
  __syncthreads();
  int nn = t >> 3, kk = (t & 7) * 4;
  ushort4 o;
  o.x = f2bf(sh[kk+0][nn]);
  o.y = f2bf(sh[kk+1][nn]);
  o.z = f2bf(sh[kk+2][nn]);
  o.w = f2bf(sh[kk+3][nn]);
  *(ushort4*)&((unsigned short*)d)[(long)(n0+nn)*K + k0 + kk] = o;
}

// ---------------- embedding + LN (writes f32 h + bf16 hb) ----------------
__global__ __launch_bounds__(256) void embed_ln_kernel(
    const int* __restrict__ ids, const float* __restrict__ tok, const float* __restrict__ pos,
    const float* __restrict__ g, const float* __restrict__ bt,
    float* __restrict__ h, __hip_bfloat16* __restrict__ hb){
  int t = threadIdx.x;
  int lane = t & 63;
  int row = blockIdx.x*4 + (t >> 6);
  int n = row & (NSEQ-1);
  int id = ids[row];
  float4 vv = ((const float4*)tok)[(long)id*64 + lane];
  float4 pv = ((const float4*)pos)[n*64 + lane];
  vv.x += pv.x; vv.y += pv.y; vv.z += pv.z; vv.w += pv.w;
  float s  = vv.x+vv.y+vv.z+vv.w;
  float s2 = vv.x*vv.x+vv.y*vv.y+vv.z*vv.z+vv.w*vv.w;
  #pragma unroll
  for(int off=1; off<64; off<<=1){ s += __shfl_xor(s, off); s2 += __shfl_xor(s2, off); }
  float mean = s*(1.f/DV);
  float var = fmaxf(s2*(1.f/DV) - mean*mean, 0.f);
  float inv = rsqrtf(var + 1e-5f);
  float4 gv = ((const float4*)g)[lane];
  float4 bv = ((const float4*)bt)[lane];
  float4 o;
  o.x=(vv.x-mean)*inv*gv.x+bv.x; o.y=(vv.y-mean)*inv*gv.y+bv.y;
  o.z=(vv.z-mean)*inv*gv.z+bv.z; o.w=(vv.w-mean)*inv*gv.w+bv.w;
  ((float4*)h)[row*64 + lane] = o;
  ushort4 ob; ob.x=f2bf(o.x); ob.y=f2bf(o.y); ob.z=f2bf(o.z); ob.w=f2bf(o.w);
  *(ushort4*)&hb[row*DV + lane*4] = ob;
}

// ---------------- (residual +) LN standalone (wave-per-row) ----------------
__global__ __launch_bounds__(256) void ln_res_kernel(
    const float* __restrict__ x, const float* __restrict__ r,
    float* __restrict__ out, __hip_bfloat16* __restrict__ outb,
    const float* __restrict__ g, const float* __restrict__ bt){
  int t = threadIdx.x;
  int lane = t & 63;
  int row = blockIdx.x*4 + (t >> 6);
  float4 vv = ((const float4*)x)[row*64 + lane];
  float4 rv = ((const float4*)r)[row*64 + lane];
  vv.x += rv.x; vv.y += rv.y; vv.z += rv.z; vv.w += rv.w;
  float s  = vv.x+vv.y+vv.z+vv.w;
  float s2 = vv.x*vv.x+vv.y*vv.y+vv.z*vv.z+vv.w*vv.w;
  #pragma unroll
  for(int off=1; off<64; off<<=1){ s += __shfl_xor(s, off); s2 += __shfl_xor(s2, off); }
  float mean = s*(1.f/DV);
  float var = fmaxf(s2*(1.f/DV) - mean*mean, 0.f);
  float inv = rsqrtf(var + 1e-5f);
  float4 gv = ((const float4*)g)[lane];
  float4 bv = ((const float4*)bt)[lane];
  float4 o;
  o.x=(vv.x-mean)*inv*gv.x+bv.x; o.y=(vv.y-mean)*inv*gv.y+bv.y;
  o.z=(vv.z-mean)*inv*gv.z+bv.z; o.w=(vv.w-mean)*inv*gv.w+bv.w;
  ((float4*)out)[row*64 + lane] = o;
  ushort4 ob; ob.x=f2bf(o.x); ob.y=f2bf(o.y); ob.z=f2bf(o.z); ob.w=f2bf(o.w);
  *(ushort4*)&outb[row*DV + lane*4] = ob;
}

// ---------------- generic pipelined bf16 MFMA GEMM, BK=64 (4 blocks/CU) ----------------
template<int WM, int WN, int FM, int FN, int ACT, int OUT_BF16, int PHASE>
__global__ __launch_bounds__(256) void mfma_gemm(
    const __hip_bfloat16* __restrict__ A, const __hip_bfloat16* __restrict__ Bt,
    const float* __restrict__ bias, void* __restrict__ Cout,
    int M, int N, int K, int ldc,
    const float* __restrict__ pb, float* __restrict__ cph, float* __restrict__ sph){
  constexpr int BM = WM*FM*16;
  constexpr int BN = WN*FN*16;
  constexpr int TPRA = 256/BM;     // threads per A-row
  constexpr int JA = 8/TPRA;       // short8v per thread (64 shorts/row)
  constexpr int TPRB = 256/BN;
  constexpr int JB = 8/TPRB;
  __shared__ short As[2][BM][72];
  __shared__ short Bs[2][BN][72];
  int tm = blockIdx.x*BM, tn = blockIdx.y*BN;
  int t = threadIdx.x;
  int lane = t & 63, w = t >> 6;
  int wm = w / WN, wn = w % WN;
  int lr = lane & 15, lg = lane >> 4;
  f32x4 acc[FM][FN] = {};
  const short* gA = (const short*)A;
  const short* gB = (const short*)Bt;
  int ra = t / TPRA, ca = t % TPRA;
  int rb = t / TPRB, cb = t % TPRB;
  short8v ar[JA], br[JB];
#define LOADC(K0) { const short* pa = &gA[(long)(tm+ra)*K + (K0)]; \
    _Pragma("unroll") for(int j=0;j<JA;j++) ar[j] = *(const short8v*)&pa[(ca+TPRA*j)*8]; \
    const short* pbp = &gB[(long)(tn+rb)*K + (K0)]; \
    _Pragma("unroll") for(int j=0;j<JB;j++) br[j] = *(const short8v*)&pbp[(cb+TPRB*j)*8]; }
#define STOREC(BUF) { _Pragma("unroll") for(int j=0;j<JA;j++) *(short8v*)&As[BUF][ra][(ca+TPRA*j)*8] = ar[j]; \
    _Pragma("unroll") for(int j=0;j<JB;j++) *(short8v*)&Bs[BUF][rb][(cb+TPRB*j)*8] = br[j]; }
  int nch = K >> 6;
  LOADC(0);
  STOREC(0);
  LOADC(64);
  __syncthreads();
  for(int c=0; c<nch; c++){
    int cur = c & 1;
    #pragma unroll
    for(int ks=0; ks<2; ks++){
      short8v af[FM], bf[FN];
      #pragma unroll
      for(int i=0;i<FM;i++) af[i] = *(const short8v*)&As[cur][wm*FM*16 + i*16 + lr][ks*32 + lg*8];
      #pragma unroll
      for(int j=0;j<FN;j++) bf[j] = *(const short8v*)&Bs[cur][wn*FN*16 + j*16 + lr][ks*32 + lg*8];
      #pragma unroll
      for(int i=0;i<FM;i++)
        #pragma unroll
        for(int j=0;j<FN;j++)
          acc[i][j] = __builtin_amdgcn_mfma_f32_16x16x32_bf16(af[i], bf[j], acc[i][j], 0,0,0);
    }
    if(c+1 < nch){
      STOREC(cur^1);
      if(c+2 < nch) LOADC((c+2)*64);
    }
    __syncthreads();
  }
#undef LOADC
#undef STOREC
  if(PHASE && tn >= N - 64){
    #pragma unroll
    for(int fn=0; fn<FN; fn++){
      int colr = wn*FN*16 + fn*16 + lr;
      if(colr < 8){
        float bb = pb[colr];
        #pragma unroll
        for(int fm=0; fm<FM; fm++){
          int row0 = tm + wm*FM*16 + fm*16 + lg*4;
          #pragma unroll
          for(int r2=0; r2<4; r2++){
            float ph = acc[fm][fn][r2] + bb;
            float sv, cv;
            __sincosf(ph, &sv, &cv);
            int row = row0 + r2;
            int b = row >> 10, n = row & 1023;
            int idx = (b*HHEADS + colr)*NSEQ + n;
            cph[idx] = cv; sph[idx] = sv;
          }
        }
      }
    }
    return;
  }
  #pragma unroll
  for(int fn=0; fn<FN; fn++){
    int col = tn + wn*FN*16 + fn*16 + lr;
    float bs = bias ? bias[col] : 0.f;
    #pragma unroll
    for(int fm=0; fm<FM; fm++){
      int row0 = tm + wm*FM*16 + fm*16 + lg*4;
      #pragma unroll
      for(int r2=0; r2<4; r2++){
        float xx = acc[fm][fn][r2] + bs;
        if(ACT == 1) xx = 0.5f*xx*(1.f + erff(xx*0.70710678118654752f));
        long idx = (long)(row0+r2)*ldc + col;
        if(OUT_BF16) ((__hip_bfloat16*)Cout)[idx] = __float2bfloat16(xx);
        else         ((float*)Cout)[idx] = xx;
      }
    }
  }
}

// ---------------- MFMA flash attention: split-K x4, static softmax,
// single-buffered LDS + reg-held next tile (26.5 KB LDS -> ~4 blocks/CU) ----------------
__global__ __launch_bounds__(256) void attn_mfma_kernel(
    const __hip_bfloat16* __restrict__ qkv,
    const float* __restrict__ cph, const float* __restrict__ sph,
    __hip_bfloat16* __restrict__ po, float* __restrict__ ml){
  __shared__ __align__(16) short K2[64][104];
  __shared__ __align__(16) short V2[32][72];
  __shared__ __align__(16) short Pp[4][16][72];
  int bid = blockIdx.x;
  int bh = bid >> 6;
  int qt = (bid >> 2) & 15;
  int ks = bid & 3;
  int b = bh >> 3, hh = bh & 7;
  int t = threadIdx.x;
  int lane = t & 63, w = t >> 6;
  int lr = lane & 15, lg = lane >> 4;
  int q0w = qt*64 + w*16;

  const unsigned short* qrow = (const unsigned short*)qkv
      + ((long)(b*NSEQ + q0w + lr))*768 + hh*32 + lg*8;
  short8v qraw = *(const short8v*)qrow;
  float ci = cph[bh*NSEQ + q0w + lr];
  float si = sph[bh*NSEQ + q0w + lr];
  short8v qf0, qf1, qf2;
  #pragma unroll
  for(int i=0;i<8;i++){
    float x = bfbits2f((unsigned short)qraw[i]) * (0.5f*QKSCALE);
    qf0[i] = (short)f2bf(x);
    qf1[i] = (short)f2bf(x*ci);
    qf2[i] = (short)f2bf(x*si);
  }

  int srow = t >> 2, sdc = (t & 3) * 8;
  int j0b = ks*4;
  short8v kvA, vvA, kvB, vvB; float cjA, sjA, cjB, sjB;
#define LOADT(KV,VV,CJ,SJ,J) { long rg = (long)(b*NSEQ + (J)*64 + srow)*768; \
    KV = *(const short8v*)((const unsigned short*)qkv + rg + 256 + hh*32 + sdc); \
    VV = *(const short8v*)((const unsigned short*)qkv + rg + 512 + hh*32 + sdc); \
    CJ = cph[bh*NSEQ + (J)*64 + srow]; SJ = sph[bh*NSEQ + (J)*64 + srow]; }
#define STORET(KV,VV,CJ,SJ) { short8v kc, ksv; \
    _Pragma("unroll") for(int i=0;i<8;i++){ float x = bfbits2f((unsigned short)KV[i]); \
      kc[i] = (short)f2bf(x*CJ); ksv[i] = (short)f2bf(x*SJ); } \
    *(short8v*)&K2[srow][sdc]    = KV; \
    *(short8v*)&K2[srow][32+sdc] = kc; \
    *(short8v*)&K2[srow][64+sdc] = ksv; \
    _Pragma("unroll") for(int i=0;i<8;i++) V2[sdc+i][srow] = VV[i]; }

  float l = 0.f;
  f32x4 acc[2] = {};

#define ROUND(PF) { \
    f32x4 st[4]; \
    _Pragma("unroll") for(int kt=0; kt<4; kt++){ \
      short8v a0 = *(const short8v*)&K2[kt*16+lr][lg*8]; \
      short8v a1 = *(const short8v*)&K2[kt*16+lr][32+lg*8]; \
      short8v a2 = *(const short8v*)&K2[kt*16+lr][64+lg*8]; \
      f32x4 z = {0.f,0.f,0.f,0.f}; \
      z = __builtin_amdgcn_mfma_f32_16x16x32_bf16(a0, qf0, z, 0,0,0); \
      z = __builtin_amdgcn_mfma_f32_16x16x32_bf16(a1, qf1, z, 0,0,0); \
      z = __builtin_amdgcn_mfma_f32_16x16x32_bf16(a2, qf2, z, 0,0,0); \
      st[kt] = z; \
    } \
    PF; \
    float ls = 0.f; \
    _Pragma("unroll") for(int kt=0; kt<4; kt++){ \
      float p0 = __expf(st[kt][0]); \
      float p1 = __expf(st[kt][1]); \
      float p2 = __expf(st[kt][2]); \
      float p3 = __expf(st[kt][3]); \
      ls += (p0+p1)+(p2+p3); \
      unsigned int w0 = (unsigned)f2bf(p0) | ((unsigned)f2bf(p1)<<16); \
      unsigned int w1 = (unsigned)f2bf(p2) | ((unsigned)f2bf(p3)<<16); \
      unsigned int* pp = (unsigned int*)&Pp[w][lr][kt*16 + lg*4]; \
      pp[0] = w0; pp[1] = w1; \
    } \
    ls += __shfl_xor(ls, 16); \
    ls += __shfl_xor(ls, 32); \
    l += ls; \
    _Pragma("unroll") for(int kk=0; kk<2; kk++){ \
      short8v pa  = *(const short8v*)&Pp[w][lr][kk*32 + lg*8]; \
      short8v vf0 = *(const short8v*)&V2[lr][kk*32 + lg*8]; \
      short8v vf1 = *(const short8v*)&V2[16+lr][kk*32 + lg*8]; \
      acc[0] = __builtin_amdgcn_mfma_f32_16x16x32_bf16(pa, vf0, acc[0], 0,0,0); \
      acc[1] = __builtin_amdgcn_mfma_f32_16x16x32_bf16(pa, vf1, acc[1], 0,0,0); \
    } }

  LOADT(kvA, vvA, cjA, sjA, j0b);
  STORET(kvA, vvA, cjA, sjA);
  LOADT(kvB, vvB, cjB, sjB, j0b+1);
  __syncthreads();
  // round 0 (tile j0b), prefetch j0b+2 into A-regs
  ROUND( LOADT(kvA, vvA, cjA, sjA, j0b+2) );
  __syncthreads();
  STORET(kvB, vvB, cjB, sjB);
  __syncthreads();
  // round 1 (tile j0b+1), prefetch j0b+3 into B-regs
  ROUND( LOADT(kvB, vvB, cjB, sjB, j0b+3) );
  __syncthreads();
  STORET(kvA, vvA, cjA, sjA);
  __syncthreads();
  // round 2 (tile j0b+2)
  ROUND(;);
  __syncthreads();
  STORET(kvB, vvB, cjB, sjB);
  __syncthreads();
  // round 3 (tile j0b+3)
  ROUND(;);
#undef LOADT
#undef STORET
#undef ROUND
  if(lane < 16){
    ml[((long)(ks*16+bh))*NSEQ + q0w + lr] = l;
  }
  #pragma unroll
  for(int dt=0; dt<2; dt++)
    #pragma unroll
    for(int r=0;r<4;r++){
      int row = q0w + lg*4 + r;
      po[(((long)(ks*16+bh))*NSEQ + row)*32 + dt*16 + lr] =
          __float2bfloat16(acc[dt][r]);
    }
}

// ---------------- wo_ln: combine(x4) + @Wo + residual + LN1, 16-row stripes ----------------
__global__ __launch_bounds__(256) void wo_ln_kernel(
    const __hip_bfloat16* __restrict__ po, const float* __restrict__ ml,
    const __hip_bfloat16* __restrict__ Bt, const float* __restrict__ hres,
    const float* __restrict__ lng, const float* __restrict__ lnb,
    float* __restrict__ h1, __hip_bfloat16* __restrict__ hb1){
  __shared__ short As[16][264];
  __shared__ short Bs[64][264];
  __shared__ float Co[16][260];
  int tm = blockIdx.x*16;
  int t = threadIdx.x;
  int lane = t & 63, w = t >> 6;
  int lr = lane & 15, lg = lane >> 4;
  {
    int r = t >> 4;
    int c16 = (t & 15) * 16;
    int R = tm + r; int b = R >> 10, q = R & 1023;
    int bh = b*HHEADS + (c16 >> 5);
    long mlb = (long)bh*NSEQ + q;
    float lsum = ml[mlb] + ml[mlb + 16*NSEQ] + ml[mlb + 32*NSEQ] + ml[mlb + 48*NSEQ];
    float inv = 1.f/lsum;
    long pob = ((long)bh*NSEQ + q)*32 + (c16 & 31);
    const unsigned short* pp = (const unsigned short*)po;
    #pragma unroll
    for(int i=0;i<2;i++){
      short8v a0 = *(const short8v*)&pp[pob + i*8];
      short8v a1 = *(const short8v*)&pp[pob + (long)16*NSEQ*32 + i*8];
      short8v a2 = *(const short8v*)&pp[pob + (long)32*NSEQ*32 + i*8];
      short8v a3 = *(const short8v*)&pp[pob + (long)48*NSEQ*32 + i*8];
      short8v o;
      #pragma unroll
      for(int k=0;k<8;k++)
        o[k] = (short)f2bf((bfbits2f((unsigned short)a0[k]) + bfbits2f((unsigned short)a1[k])
                          + bfbits2f((unsigned short)a2[k]) + bfbits2f((unsigned short)a3[k]))*inv);
      *(short8v*)&As[r][c16 + i*8] = o;
    }
  }
  const short* gB = (const short*)Bt;
  int rb = t >> 2, cb = t & 3;
  {
    const short* pbp = &gB[(long)rb*256];
    #pragma unroll
    for(int j=0;j<8;j++) *(short8v*)&Bs[rb][(cb+4*j)*8] = *(const short8v*)&pbp[(cb+4*j)*8];
  }
  __syncthreads();
  f32x4 acc[4] = {};
  for(int ct=0; ct<4; ct++){
    #pragma unroll
    for(int ksx=0; ksx<8; ksx++){
      short8v af = *(const short8v*)&As[lr][ksx*32 + lg*8];
      short8v bf = *(const short8v*)&Bs[w*16+lr][ksx*32 + lg*8];
      acc[ct] = __builtin_amdgcn_mfma_f32_16x16x32_bf16(af, bf, acc[ct], 0,0,0);
    }
    if(ct < 3){
      __syncthreads();
      const short* pbp = &gB[(long)((ct+1)*64 + rb)*256];
      #pragma unroll
      for(int j=0;j<8;j++) *(short8v*)&Bs[rb][(cb+4*j)*8] = *(const short8v*)&pbp[(cb+4*j)*8];
      __syncthreads();
    }
  }
  #pragma unroll
  for(int ct=0; ct<4; ct++)
    #pragma unroll
    for(int r2=0; r2<4; r2++)
      Co[lg*4 + r2][ct*64 + w*16 + lr] = acc[ct][r2];
  __syncthreads();
  {
    int r = t >> 4;
    int c16 = (t & 15) * 16;
    int R = tm + r;
    float v[16];
    float s = 0.f, s2 = 0.f;
    const float* hr = hres + (long)R*DV + c16;
    #pragma unroll
    for(int i=0;i<4;i++){
      float4 hv = *(const float4*)&hr[4*i];
      float x0 = Co[r][c16+4*i]   + hv.x;
      float x1 = Co[r][c16+4*i+1] + hv.y;
      float x2 = Co[r][c16+4*i+2] + hv.z;
      float x3 = Co[r][c16+4*i+3] + hv.w;
      v[4*i]=x0; v[4*i+1]=x1; v[4*i+2]=x2; v[4*i+3]=x3;
      s += x0+x1+x2+x3;
      s2 += x0*x0+x1*x1+x2*x2+x3*x3;
    }
    s += __shfl_xor(s,1); s2 += __shfl_xor(s2,1);
    s += __shfl_xor(s,2); s2 += __shfl_xor(s2,2);
    s += __shfl_xor(s,4); s2 += __shfl_xor(s2,4);
    s += __shfl_xor(s,8); s2 += __shfl_xor(s2,8);
    float mean = s*(1.f/DV);
    float var = fmaxf(s2*(1.f/DV) - mean*mean, 0.f);
    float invs = rsqrtf(var + 1e-5f);
    #pragma unroll
    for(int i=0;i<4;i++){
      int col = c16 + 4*i;
      float4 gv = *(const float4*)&lng[col];
      float4 bv = *(const float4*)&lnb[col];
      float o0 = (v[4*i+0]-mean)*invs*gv.x + bv.x;
      float o1 = (v[4*i+1]-mean)*invs*gv.y + bv.y;
      float o2 = (v[4*i+2]-mean)*invs*gv.z + bv.z;
      float o3 = (v[4*i+3]-mean)*invs*gv.w + bv.w;
      *(float4*)&h1[(long)R*DV + col] = make_float4(o0,o1,o2,o3);
      ushort4 ob; ob.x=f2bf(o0); ob.y=f2bf(o1); ob.z=f2bf(o2); ob.w=f2bf(o3);
      *(ushort4*)&hb1[(long)R*DV + col] = ob;
    }
  }
}

// ---------------- final: LN2 -> outLN -> column partial sums ----------------
__global__ __launch_bounds__(256) void final_pool_kernel(
    const float* __restrict__ x, const float* __restrict__ r,
    const float* __restrict__ g2, const float* __restrict__ b2,
    const float* __restrict__ og, const float* __restrict__ ob,
    float* __restrict__ part){
  __shared__ float ws2[32][260];
  int t = threadIdx.x;
  int lrow = t >> 3;
  int row = blockIdx.x*32 + lrow;
  int c0 = (t & 7) * 32;
  float v[32];
  float s=0.f, s2=0.f;
  const float* xr = x + (long)row*DV + c0;
  const float* rr = r + (long)row*DV + c0;
  #pragma unroll
  for(int i=0;i<8;i++){
    float4 xv = *(const float4*)&xr[4*i];
    float4 rv = *(const float4*)&rr[4*i];
    xv.x+=rv.x; xv.y+=rv.y; xv.z+=rv.z; xv.w+=rv.w;
    v[4*i]=xv.x; v[4*i+1]=xv.y; v[4*i+2]=xv.z; v[4*i+3]=xv.w;
    s += xv.x+xv.y+xv.z+xv.w;
    s2 += xv.x*xv.x+xv.y*xv.y+xv.z*xv.z+xv.w*xv.w;
  }
  s += __shfl_xor(s,1); s2 += __shfl_xor(s2,1);
  s += __shfl_xor(s,2); s2 += __shfl_xor(s2,2);
  s += __shfl_xor(s,4); s2 += __shfl_xor(s2,4);
  float mean = s*(1.f/DV);
  float var = fmaxf(s2*(1.f/DV)-mean*mean, 0.f);
  float inv = rsqrtf(var + 1e-5f);
  float s_=0.f, s2_=0.f;
  #pragma unroll
  for(int i=0;i<32;i++){
    int col = c0 + i;
    float o = (v[i]-mean)*inv*g2[col] + b2[col];
    v[i] = o;
    s_ += o; s2_ += o*o;
  }
  s_ += __shfl_xor(s_,1); s2_ += __shfl_xor(s2_,1);
  s_ += __shfl_xor(s_,2); s2_ += __shfl_xor(s2_,2);
  s_ += __shfl_xor(s_,4); s2_ += __shfl_xor(s2_,4);
  float mean2 = s_*(1.f/DV);
  float var2 = fmaxf(s2_*(1.f/DV)-mean2*mean2, 0.f);
  float inv2 = rsqrtf(var2 + 1e-5f);
  #pragma unroll
  for(int i=0;i<32;i++){
    int col = c0 + i;
    ws2[lrow][col] = (v[i]-mean2)*inv2*og[col] + ob[col];
  }
  __syncthreads();
  float accv = 0.f;
  #pragma unroll 8
  for(int rr2=0; rr2<32; rr2++) accv += ws2[rr2][t];
  part[blockIdx.x*DV + t] = accv;
}

// ---------------- head: reduce partials + matvec ----------------
__global__ __launch_bounds__(256) void head_kernel(
    const float* __restrict__ part, const float* __restrict__ W,
    const float* __restrict__ hb, float* __restrict__ out){
  __shared__ float pooled[2][256];
  int t = threadIdx.x;
  float a0 = 0.f, a1 = 0.f;
  #pragma unroll 8
  for(int k=0;k<32;k++){ a0 += part[k*DV + t]; a1 += part[(32+k)*DV + t]; }
  pooled[0][t] = a0 * (1.f/NSEQ);
  pooled[1][t] = a1 * (1.f/NSEQ);
  __syncthreads();
  int vcol = blockIdx.x*256 + t;
  float x0 = 0.f, x1 = 0.f;
  #pragma unroll 8
  for(int d=0; d<DV; d++){
    float wv = W[(long)d*VV + vcol];
    x0 += pooled[0][d]*wv;
    x1 += pooled[1][d]*wv;
  }
  float bb = hb[vcol];
  out[vcol] = x0 + bb;
  out[VV + vcol] = x1 + bb;
}

extern "C" void kernel_launch(void* const* d_in, const int* in_sizes, int n_in,
                              void* d_out, int out_size, void* d_ws, size_t ws_size,
                              hipStream_t stream){
  const int*   ids   = (const int*)  d_in[0];
  const float* tok   = (const float*)d_in[1];
  const float* pos   = (const float*)d_in[2];
  const float* en_g  = (const float*)d_in[3];
  const float* en_b  = (const float*)d_in[4];
  const float* Wq    = (const float*)d_in[7];
  const float* Wk    = (const float*)d_in[8];
  const float* Wv    = (const float*)d_in[9];
  const float* Wo    = (const float*)d_in[10];
  const float* pp_w  = (const float*)d_in[11];
  const float* pp_b  = (const float*)d_in[12];
  const float* f1_w  = (const float*)d_in[13];
  const float* f1_b  = (const float*)d_in[14];
  const float* f2_w  = (const float*)d_in[15];
  const float* f2_b  = (const float*)d_in[16];
  const float* ln1_g = (const float*)d_in[17];
  const float* ln1_b = (const float*)d_in[18];
  const float* ln2_g = (const float*)d_in[19];
  const float* ln2_b = (const float*)d_in[20];
  const float* on_g  = (const float*)d_in[23];
  const float* on_b  = (const float*)d_in[24];
  const float* head_w= (const float*)d_in[25];
  const float* head_b= (const float*)d_in[26];
  float* out = (float*)d_out;

  char* wsb = (char*)d_ws;
  float* h    = (float*)(wsb);
  __hip_bfloat16* hb  = (__hip_bfloat16*)(wsb + (2u<<20));
  float* h1   = (float*)(wsb + (3u<<20));
  __hip_bfloat16* hb1 = (__hip_bfloat16*)(wsb + (5u<<20));
  __hip_bfloat16* qkv = (__hip_bfloat16*)(wsb + (6u<<20));
  __hip_bfloat16* po  = (__hip_bfloat16*)(wsb + (9u<<20));
  float* mlb  = (float*)(wsb + (13u<<20));
  __hip_bfloat16* ff  = (__hip_bfloat16*)(wsb + (14u<<20));
  float* s_ff = (float*)(wsb + (18u<<20));
  float* cphb = (float*)(wsb + (20u<<20));
  float* sphb = cphb + 16384;
  float* part = sphb + 16384;
  __hip_bfloat16* wt = (__hip_bfloat16*)(wsb + (20u<<20) + (192u<<10));
  __hip_bfloat16* wqkvp = wt + OFF_WQKVP;
  __hip_bfloat16* wot   = wt + OFF_WOT;
  __hip_bfloat16* f1t   = wt + OFF_F1T;
  __hip_bfloat16* f2t   = wt + OFF_F2T;

  transpose_cvt_all<<<1552, 256, 0, stream>>>(Wq, Wk, Wv, Wo, pp_w, f1_w, f2_w, wt);
  embed_ln_kernel<<<512, 256, 0, stream>>>(ids, tok, pos, en_g, en_b, h, hb);

  for(int it=0; it<4; it++){
    int l = it & 1;
    mfma_gemm<2,2,2,2, 0,1,1><<<dim3(32,13), 256, 0, stream>>>(
        hb, wqkvp + (long)l*212992, nullptr, qkv, 2048, 832, 256, 768,
        pp_b + l*HHEADS, cphb, sphb);
    attn_mfma_kernel<<<1024, 256, 0, stream>>>(qkv, cphb, sphb, po, mlb);
    wo_ln_kernel<<<128, 256, 0, stream>>>(
        po, mlb, wot + l*65536, h, ln1_g + l*DV, ln1_b + l*DV, h1, hb1);
    mfma_gemm<2,2,2,2, 1,1,0><<<dim3(32,16), 256, 0, stream>>>(
        hb1, f1t + l*262144, f1_b + l*1024, ff, 2048, 1024, 256, 1024,
        nullptr, nullptr, nullptr);
    mfma_gemm<1,4,2,1, 0,0,0><<<dim3(64,4), 256, 0, stream>>>(
        ff, f2t + l*262144, f2_b + l*DV, s_ff, 2048, 256, 1024, 256,
        nullptr, nullptr, nullptr);
    if(it < 3)
      ln_res_kernel<<<512, 256, 0, stream>>>(s_ff, h1, h, hb, ln2_g + l*DV, ln2_b + l*DV);
  }
  final_pool_kernel<<<64, 256, 0, stream>>>(s_ff, h1, ln2_g + DV, ln2_b + DV, on_g, on_b, part);
  head_kernel<<<125, 256, 0, stream>>>(part, head_w, head_b, out);
}

// Round 10
// 204.103 us; speedup vs baseline: 1.0437x; 1.0437x over previous
//
#include <hip/hip_runtime.h>
#include <hip/hip_bf16.h>
#include <math.h>

#define DV 256
#define NSEQ 1024
#define HHEADS 8
#define VV 32000
#define QKSCALE 0.17677669529663687f  // 1/sqrt(32)

typedef __attribute__((ext_vector_type(8))) short short8v;
typedef __attribute__((ext_vector_type(4))) float f32x4;

__device__ __forceinline__ unsigned short f2bf(float f){
  __hip_bfloat16 b = __float2bfloat16(f);
  return *reinterpret_cast<unsigned short*>(&b);
}
__device__ __forceinline__ float bfbits2f(unsigned short u){
  unsigned int x = ((unsigned int)u) << 16;
  return __uint_as_float(x);
}
// XCD-aware swizzle: blocks b -> XCD b%8 (HW round-robin); remap so wid-contiguous
// work (which shares operand panels) is XCD-contiguous. Requires nwg%8==0.
__device__ __forceinline__ int xcd_swz(int lin, int nwg){
  return (lin & 7) * (nwg >> 3) + (lin >> 3);
}

#define OFF_WQKVP 0
#define OFF_WOT   425984
#define OFF_F1T   557056
#define OFF_F2T   1081344
__global__ __launch_bounds__(256) void transpose_cvt_all(
    const float* __restrict__ Wq, const float* __restrict__ Wk,
    const float* __restrict__ Wv, const float* __restrict__ Wo,
    const float* __restrict__ ppw, const float* __restrict__ f1w,
    const float* __restrict__ f2w, __hip_bfloat16* __restrict__ dst){
  __shared__ float sh[32][33];
  int bid = blockIdx.x;
  int t = threadIdx.x;
  if(bid >= 512 && bid < 528){
    int idx = bid - 512;
    int l = idx >> 3, k0 = (idx & 7) * 32;
    int rowo = t >> 2;
    int kbase = k0 + (t & 3) * 8;
    unsigned short vals[8];
    if(rowo < 8){
      int hh = rowo;
      #pragma unroll
      for(int i=0;i<8;i++) vals[i] = f2bf(ppw[(long)l*2048 + (kbase+i)*HHEADS + hh]);
    } else {
      #pragma unroll
      for(int i=0;i<8;i++) vals[i] = 0;
    }
    unsigned short* d = (unsigned short*)dst + (long)l*212992 + (768+rowo)*256 + kbase;
    #pragma unroll
    for(int i=0;i<8;i++) d[i] = vals[i];
    return;
  }
  const float* src; __hip_bfloat16* d; int K, N, tile;
  if(bid < 384){
    int l = bid / 192, rem = bid % 192, mat = rem >> 6; tile = rem & 63;
    src = (mat==0 ? Wq : (mat==1 ? Wk : Wv)) + l*65536;
    d = dst + (long)l*212992 + mat*65536;
    K = 256; N = 256;
  } else if(bid < 512){
    int b2 = bid - 384; int l = b2 >> 6; tile = b2 & 63;
    src = Wo + l*65536; d = dst + OFF_WOT + l*65536; K = 256; N = 256;
  } else if(bid < 1040){
    int b2 = bid - 528; int l = b2 >> 8; tile = b2 & 255;
    src = f1w + l*262144; d = dst + OFF_F1T + l*262144; K = 256; N = 1024;
  } else {
    int b2 = bid - 1040; int l = b2 >> 8; tile = b2 & 255;
    src = f2w + l*262144; d = dst + OFF_F2T + l*262144; K = 1024; N = 256;
  }
  int ntn = N >> 5;
  int tk = tile / ntn, tn = tile - tk*ntn;
  int k0 = tk*32, n0 = tn*32;
  {
    int rr = t >> 3, cc = (t & 7) * 4;
    float4 v = *(const float4*)&src[(long)(k0+rr)*N + n0 + cc];
    sh[rr][cc]=v.x; sh[rr][cc+1]=v.y; sh[rr][cc+2]=v.z; sh[rr][cc+3]=v.w;
  }
  __syncthreads();
  int nn = t >> 3, kk = (t & 7) * 4;
  ushort4 o;
  o.x = f2bf(sh[kk+0][nn]);
  o.y = f2bf(sh[kk+1][nn]);
  o.z = f2bf(sh[kk+2][nn]);
  o.w = f2bf(sh[kk+3][nn]);
  *(ushort4*)&((unsigned short*)d)[(long)(n0+nn)*K + k0 + kk] = o;
}

// ---------------- embedding + LN (writes f32 h + bf16 hb) ----------------
__global__ __launch_bounds__(256) void embed_ln_kernel(
    const int* __restrict__ ids, const float* __restrict__ tok, const float* __restrict__ pos,
    const float* __restrict__ g, const float* __restrict__ bt,
    float* __restrict__ h, __hip_bfloat16* __restrict__ hb){
  int t = threadIdx.x;
  int lane = t & 63;
  int row = blockIdx.x*4 + (t >> 6);
  int n = row & (NSEQ-1);
  int id = ids[row];
  float4 vv = ((const float4*)tok)[(long)id*64 + lane];
  float4 pv = ((const float4*)pos)[n*64 + lane];
  vv.x += pv.x; vv.y += pv.y; vv.z += pv.z; vv.w += pv.w;
  float s  = vv.x+vv.y+vv.z+vv.w;
  float s2 = vv.x*vv.x+vv.y*vv.y+vv.z*vv.z+vv.w*vv.w;
  #pragma unroll
  for(int off=1; off<64; off<<=1){ s += __shfl_xor(s, off); s2 += __shfl_xor(s2, off); }
  float mean = s*(1.f/DV);
  float var = fmaxf(s2*(1.f/DV) - mean*mean, 0.f);
  float inv = rsqrtf(var + 1e-5f);
  float4 gv = ((const float4*)g)[lane];
  float4 bv = ((const float4*)bt)[lane];
  float4 o;
  o.x=(vv.x-mean)*inv*gv.x+bv.x; o.y=(vv.y-mean)*inv*gv.y+bv.y;
  o.z=(vv.z-mean)*inv*gv.z+bv.z; o.w=(vv.w-mean)*inv*gv.w+bv.w;
  ((float4*)h)[row*64 + lane] = o;
  ushort4 ob; ob.x=f2bf(o.x); ob.y=f2bf(o.y); ob.z=f2bf(o.z); ob.w=f2bf(o.w);
  *(ushort4*)&hb[row*DV + lane*4] = ob;
}

// ---------------- (residual +) LN standalone (wave-per-row) ----------------
__global__ __launch_bounds__(256) void ln_res_kernel(
    const float* __restrict__ x, const float* __restrict__ r,
    float* __restrict__ out, __hip_bfloat16* __restrict__ outb,
    const float* __restrict__ g, const float* __restrict__ bt){
  int t = threadIdx.x;
  int lane = t & 63;
  int row = blockIdx.x*4 + (t >> 6);
  float4 vv = ((const float4*)x)[row*64 + lane];
  float4 rv = ((const float4*)r)[row*64 + lane];
  vv.x += rv.x; vv.y += rv.y; vv.z += rv.z; vv.w += rv.w;
  float s  = vv.x+vv.y+vv.z+vv.w;
  float s2 = vv.x*vv.x+vv.y*vv.y+vv.z*vv.z+vv.w*vv.w;
  #pragma unroll
  for(int off=1; off<64; off<<=1){ s += __shfl_xor(s, off); s2 += __shfl_xor(s2, off); }
  float mean = s*(1.f/DV);
  float var = fmaxf(s2*(1.f/DV) - mean*mean, 0.f);
  float inv = rsqrtf(var + 1e-5f);
  float4 gv = ((const float4*)g)[lane];
  float4 bv = ((const float4*)bt)[lane];
  float4 o;
  o.x=(vv.x-mean)*inv*gv.x+bv.x; o.y=(vv.y-mean)*inv*gv.y+bv.y;
  o.z=(vv.z-mean)*inv*gv.z+bv.z; o.w=(vv.w-mean)*inv*gv.w+bv.w;
  ((float4*)out)[row*64 + lane] = o;
  ushort4 ob; ob.x=f2bf(o.x); ob.y=f2bf(o.y); ob.z=f2bf(o.z); ob.w=f2bf(o.w);
  *(ushort4*)&outb[row*DV + lane*4] = ob;
}

// ---------------- generic pipelined bf16 MFMA GEMM (BK=128, R8 version) + XCD swizzle ----------------
template<int WM, int WN, int FM, int FN, int ACT, int OUT_BF16, int PHASE>
__global__ __launch_bounds__(256) void mfma_gemm(
    const __hip_bfloat16* __restrict__ A, const __hip_bfloat16* __restrict__ Bt,
    const float* __restrict__ bias, void* __restrict__ Cout,
    int M, int N, int K, int ldc,
    const float* __restrict__ pb, float* __restrict__ cph, float* __restrict__ sph){
  constexpr int BM = WM*FM*16;
  constexpr int BN = WN*FN*16;
  constexpr int TPRA = 256/BM;
  constexpr int JA = 16/TPRA;
  __shared__ short As[2][BM][136];
  __shared__ short Bs[2][BN][136];
  int nwg = gridDim.x * gridDim.y;
  int lin = blockIdx.x + blockIdx.y * gridDim.x;
  int wid = (nwg & 7) ? lin : xcd_swz(lin, nwg);
  int bx = wid % gridDim.x, by = wid / gridDim.x;
  int tm = bx*BM, tn = by*BN;
  int t = threadIdx.x;
  int lane = t & 63, w = t >> 6;
  int wm = w / WN, wn = w % WN;
  int lr = lane & 15, lg = lane >> 4;
  f32x4 acc[FM][FN] = {};
  const short* gA = (const short*)A;
  const short* gB = (const short*)Bt;
  int ra = t / TPRA, ca = t % TPRA;
  int rb = t >> 2,  cb = t & 3;
  short8v ar[JA], br[4];
#define LOADC(K0) { const short* pa = &gA[(long)(tm+ra)*K + (K0)]; \
    _Pragma("unroll") for(int j=0;j<JA;j++) ar[j] = *(const short8v*)&pa[(ca+TPRA*j)*8]; \
    const short* pbp = &gB[(long)(tn+rb)*K + (K0)]; \
    _Pragma("unroll") for(int j=0;j<4;j++) br[j] = *(const short8v*)&pbp[(cb+4*j)*8]; }
#define STOREC(BUF) { _Pragma("unroll") for(int j=0;j<JA;j++) *(short8v*)&As[BUF][ra][(ca+TPRA*j)*8] = ar[j]; \
    _Pragma("unroll") for(int j=0;j<4;j++) *(short8v*)&Bs[BUF][rb][(cb+4*j)*8] = br[j]; }
  int nch = K >> 7;
  LOADC(0);
  STOREC(0);
  if(nch > 1) LOADC(128);
  __syncthreads();
  for(int c=0; c<nch; c++){
    int cur = c & 1;
    #pragma unroll
    for(int ks=0; ks<4; ks++){
      short8v af[FM], bf[FN];
      #pragma unroll
      for(int i=0;i<FM;i++) af[i] = *(const short8v*)&As[cur][wm*FM*16 + i*16 + lr][ks*32 + lg*8];
      #pragma unroll
      for(int j=0;j<FN;j++) bf[j] = *(const short8v*)&Bs[cur][wn*FN*16 + j*16 + lr][ks*32 + lg*8];
      #pragma unroll
      for(int i=0;i<FM;i++)
        #pragma unroll
        for(int j=0;j<FN;j++)
          acc[i][j] = __builtin_amdgcn_mfma_f32_16x16x32_bf16(af[i], bf[j], acc[i][j], 0,0,0);
    }
    if(c+1 < nch){
      STOREC(cur^1);
      if(c+2 < nch) LOADC((c+2)*128);
    }
    __syncthreads();
  }
#undef LOADC
#undef STOREC
  if(PHASE && tn >= N - 64){
    #pragma unroll
    for(int fn=0; fn<FN; fn++){
      int colr = wn*FN*16 + fn*16 + lr;
      if(colr < 8){
        float bb = pb[colr];
        #pragma unroll
        for(int fm=0; fm<FM; fm++){
          int row0 = tm + wm*FM*16 + fm*16 + lg*4;
          #pragma unroll
          for(int r2=0; r2<4; r2++){
            float ph = acc[fm][fn][r2] + bb;
            float sv, cv;
            __sincosf(ph, &sv, &cv);
            int row = row0 + r2;
            int b = row >> 10, n = row & 1023;
            int idx = (b*HHEADS + colr)*NSEQ + n;
            cph[idx] = cv; sph[idx] = sv;
          }
        }
      }
    }
    return;
  }
  #pragma unroll
  for(int fn=0; fn<FN; fn++){
    int col = tn + wn*FN*16 + fn*16 + lr;
    float bs = bias ? bias[col] : 0.f;
    #pragma unroll
    for(int fm=0; fm<FM; fm++){
      int row0 = tm + wm*FM*16 + fm*16 + lg*4;
      #pragma unroll
      for(int r2=0; r2<4; r2++){
        float xx = acc[fm][fn][r2] + bs;
        if(ACT == 1) xx = 0.5f*xx*(1.f + erff(xx*0.70710678118654752f));
        long idx = (long)(row0+r2)*ldc + col;
        if(OUT_BF16) ((__hip_bfloat16*)Cout)[idx] = __float2bfloat16(xx);
        else         ((float*)Cout)[idx] = xx;
      }
    }
  }
}

// ---------------- MFMA flash attention: split-K x4, static softmax, double-buffered (R8)
// + XCD swizzle: the 64 blocks of one bh become XCD-contiguous -> K/V L2-resident ----------------
__global__ __launch_bounds__(256) void attn_mfma_kernel(
    const __hip_bfloat16* __restrict__ qkv,
    const float* __restrict__ cph, const float* __restrict__ sph,
    __hip_bfloat16* __restrict__ po, float* __restrict__ ml){
  __shared__ __align__(16) short K2[2][64][104];
  __shared__ __align__(16) short V2[2][32][72];
  __shared__ __align__(16) short Pp[4][16][72];
  int bid = xcd_swz(blockIdx.x, gridDim.x);   // 1024 % 8 == 0
  int bh = bid >> 6;
  int qt = (bid >> 2) & 15;
  int ks = bid & 3;
  int b = bh >> 3, hh = bh & 7;
  int t = threadIdx.x;
  int lane = t & 63, w = t >> 6;
  int lr = lane & 15, lg = lane >> 4;
  int q0w = qt*64 + w*16;

  const unsigned short* qrow = (const unsigned short*)qkv
      + ((long)(b*NSEQ + q0w + lr))*768 + hh*32 + lg*8;
  short8v qraw = *(const short8v*)qrow;
  float ci = cph[bh*NSEQ + q0w + lr];
  float si = sph[bh*NSEQ + q0w + lr];
  short8v qf0, qf1, qf2;
  #pragma unroll
  for(int i=0;i<8;i++){
    float x = bfbits2f((unsigned short)qraw[i]) * (0.5f*QKSCALE);
    qf0[i] = (short)f2bf(x);
    qf1[i] = (short)f2bf(x*ci);
    qf2[i] = (short)f2bf(x*si);
  }

  int srow = t >> 2, sdc = (t & 3) * 8;
  int j0b = ks*4;
  short8v kv, vvr; float cj, sj;
#define LOADT(J) { long rg = (long)(b*NSEQ + (J)*64 + srow)*768; \
    kv  = *(const short8v*)((const unsigned short*)qkv + rg + 256 + hh*32 + sdc); \
    vvr = *(const short8v*)((const unsigned short*)qkv + rg + 512 + hh*32 + sdc); \
    cj = cph[bh*NSEQ + (J)*64 + srow]; sj = sph[bh*NSEQ + (J)*64 + srow]; }
#define STORET(BUF) { short8v kc, ksv; \
    _Pragma("unroll") for(int i=0;i<8;i++){ float x = bfbits2f((unsigned short)kv[i]); \
      kc[i] = (short)f2bf(x*cj); ksv[i] = (short)f2bf(x*sj); } \
    *(short8v*)&K2[BUF][srow][sdc]    = kv; \
    *(short8v*)&K2[BUF][srow][32+sdc] = kc; \
    *(short8v*)&K2[BUF][srow][64+sdc] = ksv; \
    _Pragma("unroll") for(int i=0;i<8;i++) V2[BUF][sdc+i][srow] = vvr[i]; }

  float l = 0.f;
  f32x4 acc[2] = {};

  LOADT(j0b);
  STORET(0);
  LOADT(j0b+1);
  __syncthreads();
  for(int j=0; j<4; j++){
    int cur = j & 1;
    f32x4 st[4];
    #pragma unroll
    for(int kt=0; kt<4; kt++){
      short8v a0 = *(const short8v*)&K2[cur][kt*16+lr][lg*8];
      short8v a1 = *(const short8v*)&K2[cur][kt*16+lr][32+lg*8];
      short8v a2 = *(const short8v*)&K2[cur][kt*16+lr][64+lg*8];
      f32x4 z = {0.f,0.f,0.f,0.f};
      z = __builtin_amdgcn_mfma_f32_16x16x32_bf16(a0, qf0, z, 0,0,0);
      z = __builtin_amdgcn_mfma_f32_16x16x32_bf16(a1, qf1, z, 0,0,0);
      z = __builtin_amdgcn_mfma_f32_16x16x32_bf16(a2, qf2, z, 0,0,0);
      st[kt] = z;
    }
    float ls = 0.f;
    #pragma unroll
    for(int kt=0; kt<4; kt++){
      float p0 = __expf(st[kt][0]);
      float p1 = __expf(st[kt][1]);
      float p2 = __expf(st[kt][2]);
      float p3 = __expf(st[kt][3]);
      ls += (p0+p1)+(p2+p3);
      unsigned int w0 = (unsigned)f2bf(p0) | ((unsigned)f2bf(p1)<<16);
      unsigned int w1 = (unsigned)f2bf(p2) | ((unsigned)f2bf(p3)<<16);
      unsigned int* pp = (unsigned int*)&Pp[w][lr][kt*16 + lg*4];
      pp[0] = w0; pp[1] = w1;
    }
    ls += __shfl_xor(ls, 16);
    ls += __shfl_xor(ls, 32);
    l += ls;
    #pragma unroll
    for(int kk=0; kk<2; kk++){
      short8v pa  = *(const short8v*)&Pp[w][lr][kk*32 + lg*8];
      short8v vf0 = *(const short8v*)&V2[cur][lr][kk*32 + lg*8];
      short8v vf1 = *(const short8v*)&V2[cur][16+lr][kk*32 + lg*8];
      acc[0] = __builtin_amdgcn_mfma_f32_16x16x32_bf16(pa, vf0, acc[0], 0,0,0);
      acc[1] = __builtin_amdgcn_mfma_f32_16x16x32_bf16(pa, vf1, acc[1], 0,0,0);
    }
    if(j < 3){
      STORET(cur^1);
      if(j < 2) LOADT(j0b+j+2);
    }
    __syncthreads();
  }
#undef LOADT
#undef STORET
  if(lane < 16){
    ml[((long)(ks*16+bh))*NSEQ + q0w + lr] = l;
  }
  #pragma unroll
  for(int dt=0; dt<2; dt++)
    #pragma unroll
    for(int r=0;r<4;r++){
      int row = q0w + lg*4 + r;
      po[(((long)(ks*16+bh))*NSEQ + row)*32 + dt*16 + lr] =
          __float2bfloat16(acc[dt][r]);
    }
}

// ---------------- wo_ln: combine(x4) + @Wo + residual + LN1, 16-row stripes ----------------
__global__ __launch_bounds__(256) void wo_ln_kernel(
    const __hip_bfloat16* __restrict__ po, const float* __restrict__ ml,
    const __hip_bfloat16* __restrict__ Bt, const float* __restrict__ hres,
    const float* __restrict__ lng, const float* __restrict__ lnb,
    float* __restrict__ h1, __hip_bfloat16* __restrict__ hb1){
  __shared__ short As[16][264];
  __shared__ short Bs[64][264];
  __shared__ float Co[16][260];
  int tm = blockIdx.x*16;
  int t = threadIdx.x;
  int lane = t & 63, w = t >> 6;
  int lr = lane & 15, lg = lane >> 4;
  {
    int r = t >> 4;
    int c16 = (t & 15) * 16;
    int R = tm + r; int b = R >> 10, q = R & 1023;
    int bh = b*HHEADS + (c16 >> 5);
    long mlb = (long)bh*NSEQ + q;
    float lsum = ml[mlb] + ml[mlb + 16*NSEQ] + ml[mlb + 32*NSEQ] + ml[mlb + 48*NSEQ];
    float inv = 1.f/lsum;
    long pob = ((long)bh*NSEQ + q)*32 + (c16 & 31);
    const unsigned short* pp = (const unsigned short*)po;
    #pragma unroll
    for(int i=0;i<2;i++){
      short8v a0 = *(const short8v*)&pp[pob + i*8];
      short8v a1 = *(const short8v*)&pp[pob + (long)16*NSEQ*32 + i*8];
      short8v a2 = *(const short8v*)&pp[pob + (long)32*NSEQ*32 + i*8];
      short8v a3 = *(const short8v*)&pp[pob + (long)48*NSEQ*32 + i*8];
      short8v o;
      #pragma unroll
      for(int k=0;k<8;k++)
        o[k] = (short)f2bf((bfbits2f((unsigned short)a0[k]) + bfbits2f((unsigned short)a1[k])
                          + bfbits2f((unsigned short)a2[k]) + bfbits2f((unsigned short)a3[k]))*inv);
      *(short8v*)&As[r][c16 + i*8] = o;
    }
  }
  const short* gB = (const short*)Bt;
  int rb = t >> 2, cb = t & 3;
  {
    const short* pbp = &gB[(long)rb*256];
    #pragma unroll
    for(int j=0;j<8;j++) *(short8v*)&Bs[rb][(cb+4*j)*8] = *(const short8v*)&pbp[(cb+4*j)*8];
  }
  __syncthreads();
  f32x4 acc[4] = {};
  for(int ct=0; ct<4; ct++){
    #pragma unroll
    for(int ksx=0; ksx<8; ksx++){
      short8v af = *(const short8v*)&As[lr][ksx*32 + lg*8];
      short8v bf = *(const short8v*)&Bs[w*16+lr][ksx*32 + lg*8];
      acc[ct] = __builtin_amdgcn_mfma_f32_16x16x32_bf16(af, bf, acc[ct], 0,0,0);
    }
    if(ct < 3){
      __syncthreads();
      const short* pbp = &gB[(long)((ct+1)*64 + rb)*256];
      #pragma unroll
      for(int j=0;j<8;j++) *(short8v*)&Bs[rb][(cb+4*j)*8] = *(const short8v*)&pbp[(cb+4*j)*8];
      __syncthreads();
    }
  }
  #pragma unroll
  for(int ct=0; ct<4; ct++)
    #pragma unroll
    for(int r2=0; r2<4; r2++)
      Co[lg*4 + r2][ct*64 + w*16 + lr] = acc[ct][r2];
  __syncthreads();
  {
    int r = t >> 4;
    int c16 = (t & 15) * 16;
    int R = tm + r;
    float v[16];
    float s = 0.f, s2 = 0.f;
    const float* hr = hres + (long)R*DV + c16;
    #pragma unroll
    for(int i=0;i<4;i++){
      float4 hv = *(const float4*)&hr[4*i];
      float x0 = Co[r][c16+4*i]   + hv.x;
      float x1 = Co[r][c16+4*i+1] + hv.y;
      float x2 = Co[r][c16+4*i+2] + hv.z;
      float x3 = Co[r][c16+4*i+3] + hv.w;
      v[4*i]=x0; v[4*i+1]=x1; v[4*i+2]=x2; v[4*i+3]=x3;
      s += x0+x1+x2+x3;
      s2 += x0*x0+x1*x1+x2*x2+x3*x3;
    }
    s += __shfl_xor(s,1); s2 += __shfl_xor(s2,1);
    s += __shfl_xor(s,2); s2 += __shfl_xor(s2,2);
    s += __shfl_xor(s,4); s2 += __shfl_xor(s2,4);
    s += __shfl_xor(s,8); s2 += __shfl_xor(s2,8);
    float mean = s*(1.f/DV);
    float var = fmaxf(s2*(1.f/DV) - mean*mean, 0.f);
    float invs = rsqrtf(var + 1e-5f);
    #pragma unroll
    for(int i=0;i<4;i++){
      int col = c16 + 4*i;
      float4 gv = *(const float4*)&lng[col];
      float4 bv = *(const float4*)&lnb[col];
      float o0 = (v[4*i+0]-mean)*invs*gv.x + bv.x;
      float o1 = (v[4*i+1]-mean)*invs*gv.y + bv.y;
      float o2 = (v[4*i+2]-mean)*invs*gv.z + bv.z;
      float o3 = (v[4*i+3]-mean)*invs*gv.w + bv.w;
      *(float4*)&h1[(long)R*DV + col] = make_float4(o0,o1,o2,o3);
      ushort4 ob; ob.x=f2bf(o0); ob.y=f2bf(o1); ob.z=f2bf(o2); ob.w=f2bf(o3);
      *(ushort4*)&hb1[(long)R*DV + col] = ob;
    }
  }
}

// ---------------- final: LN2 -> outLN -> column partial sums ----------------
__global__ __launch_bounds__(256) void final_pool_kernel(
    const float* __restrict__ x, const float* __restrict__ r,
    const float* __restrict__ g2, const float* __restrict__ b2,
    const float* __restrict__ og, const float* __restrict__ ob,
    float* __restrict__ part){
  __shared__ float ws2[32][260];
  int t = threadIdx.x;
  int lrow = t >> 3;
  int row = blockIdx.x*32 + lrow;
  int c0 = (t & 7) * 32;
  float v[32];
  float s=0.f, s2=0.f;
  const float* xr = x + (long)row*DV + c0;
  const float* rr = r + (long)row*DV + c0;
  #pragma unroll
  for(int i=0;i<8;i++){
    float4 xv = *(const float4*)&xr[4*i];
    float4 rv = *(const float4*)&rr[4*i];
    xv.x+=rv.x; xv.y+=rv.y; xv.z+=rv.z; xv.w+=rv.w;
    v[4*i]=xv.x; v[4*i+1]=xv.y; v[4*i+2]=xv.z; v[4*i+3]=xv.w;
    s += xv.x+xv.y+xv.z+xv.w;
    s2 += xv.x*xv.x+xv.y*xv.y+xv.z*xv.z+xv.w*xv.w;
  }
  s += __shfl_xor(s,1); s2 += __shfl_xor(s2,1);
  s += __shfl_xor(s,2); s2 += __shfl_xor(s2,2);
  s += __shfl_xor(s,4); s2 += __shfl_xor(s2,4);
  float mean = s*(1.f/DV);
  float var = fmaxf(s2*(1.f/DV)-mean*mean, 0.f);
  float inv = rsqrtf(var + 1e-5f);
  float s_=0.f, s2_=0.f;
  #pragma unroll
  for(int i=0;i<32;i++){
    int col = c0 + i;
    float o = (v[i]-mean)*inv*g2[col] + b2[col];
    v[i] = o;
    s_ += o; s2_ += o*o;
  }
  s_ += __shfl_xor(s_,1); s2_ += __shfl_xor(s2_,1);
  s_ += __shfl_xor(s_,2); s2_ += __shfl_xor(s2_,2);
  s_ += __shfl_xor(s_,4); s2_ += __shfl_xor(s2_,4);
  float mean2 = s_*(1.f/DV);
  float var2 = fmaxf(s2_*(1.f/DV)-mean2*mean2, 0.f);
  float inv2 = rsqrtf(var2 + 1e-5f);
  #pragma unroll
  for(int i=0;i<32;i++){
    int col = c0 + i;
    ws2[lrow][col] = (v[i]-mean2)*inv2*og[col] + ob[col];
  }
  __syncthreads();
  float accv = 0.f;
  #pragma unroll 8
  for(int rr2=0; rr2<32; rr2++) accv += ws2[rr2][t];
  part[blockIdx.x*DV + t] = accv;
}

// ---------------- head: reduce partials + matvec (250 blocks x 128 thr, 2x CU coverage) ----------------
__global__ __launch_bounds__(128) void head_kernel(
    const float* __restrict__ part, const float* __restrict__ W,
    const float* __restrict__ hb, float* __restrict__ out){
  __shared__ float pooled[2][256];
  int t = threadIdx.x;
  for(int cc=t; cc<256; cc+=128){
    float a0 = 0.f, a1 = 0.f;
    #pragma unroll 8
    for(int k=0;k<32;k++){ a0 += part[k*DV + cc]; a1 += part[(32+k)*DV + cc]; }
    pooled[0][cc] = a0 * (1.f/NSEQ);
    pooled[1][cc] = a1 * (1.f/NSEQ);
  }
  __syncthreads();
  int vcol = blockIdx.x*128 + t;
  float x0 = 0.f, x1 = 0.f;
  #pragma unroll 8
  for(int d=0; d<DV; d++){
    float wv = W[(long)d*VV + vcol];
    x0 += pooled[0][d]*wv;
    x1 += pooled[1][d]*wv;
  }
  float bb = hb[vcol];
  out[vcol] = x0 + bb;
  out[VV + vcol] = x1 + bb;
}

extern "C" void kernel_launch(void* const* d_in, const int* in_sizes, int n_in,
                              void* d_out, int out_size, void* d_ws, size_t ws_size,
                              hipStream_t stream){
  const int*   ids   = (const int*)  d_in[0];
  const float* tok   = (const float*)d_in[1];
  const float* pos   = (const float*)d_in[2];
  const float* en_g  = (const float*)d_in[3];
  const float* en_b  = (const float*)d_in[4];
  const float* Wq    = (const float*)d_in[7];
  const float* Wk    = (const float*)d_in[8];
  const float* Wv    = (const float*)d_in[9];
  const float* Wo    = (const float*)d_in[10];
  const float* pp_w  = (const float*)d_in[11];
  const float* pp_b  = (const float*)d_in[12];
  const float* f1_w  = (const float*)d_in[13];
  const float* f1_b  = (const float*)d_in[14];
  const float* f2_w  = (const float*)d_in[15];
  const float* f2_b  = (const float*)d_in[16];
  const float* ln1_g = (const float*)d_in[17];
  const float* ln1_b = (const float*)d_in[18];
  const float* ln2_g = (const float*)d_in[19];
  const float* ln2_b = (const float*)d_in[20];
  const float* on_g  = (const float*)d_in[23];
  const float* on_b  = (const float*)d_in[24];
  const float* head_w= (const float*)d_in[25];
  const float* head_b= (const float*)d_in[26];
  float* out = (float*)d_out;

  char* wsb = (char*)d_ws;
  float* h    = (float*)(wsb);
  __hip_bfloat16* hb  = (__hip_bfloat16*)(wsb + (2u<<20));
  float* h1   = (float*)(wsb + (3u<<20));
  __hip_bfloat16* hb1 = (__hip_bfloat16*)(wsb + (5u<<20));
  __hip_bfloat16* qkv = (__hip_bfloat16*)(wsb + (6u<<20));
  __hip_bfloat16* po  = (__hip_bfloat16*)(wsb + (9u<<20));
  float* mlb  = (float*)(wsb + (13u<<20));
  __hip_bfloat16* ff  = (__hip_bfloat16*)(wsb + (14u<<20));
  float* s_ff = (float*)(wsb + (18u<<20));
  float* cphb = (float*)(wsb + (20u<<20));
  float* sphb = cphb + 16384;
  float* part = sphb + 16384;
  __hip_bfloat16* wt = (__hip_bfloat16*)(wsb + (20u<<20) + (192u<<10));
  __hip_bfloat16* wqkvp = wt + OFF_WQKVP;
  __hip_bfloat16* wot   = wt + OFF_WOT;
  __hip_bfloat16* f1t   = wt + OFF_F1T;
  __hip_bfloat16* f2t   = wt + OFF_F2T;

  transpose_cvt_all<<<1552, 256, 0, stream>>>(Wq, Wk, Wv, Wo, pp_w, f1_w, f2_w, wt);
  embed_ln_kernel<<<512, 256, 0, stream>>>(ids, tok, pos, en_g, en_b, h, hb);

  for(int it=0; it<4; it++){
    int l = it & 1;
    mfma_gemm<2,2,2,2, 0,1,1><<<dim3(32,13), 256, 0, stream>>>(
        hb, wqkvp + (long)l*212992, nullptr, qkv, 2048, 832, 256, 768,
        pp_b + l*HHEADS, cphb, sphb);
    attn_mfma_kernel<<<1024, 256, 0, stream>>>(qkv, cphb, sphb, po, mlb);
    wo_ln_kernel<<<128, 256, 0, stream>>>(
        po, mlb, wot + l*65536, h, ln1_g + l*DV, ln1_b + l*DV, h1, hb1);
    mfma_gemm<2,2,2,2, 1,1,0><<<dim3(32,16), 256, 0, stream>>>(
        hb1, f1t + l*262144, f1_b + l*1024, ff, 2048, 1024, 256, 1024,
        nullptr, nullptr, nullptr);
    mfma_gemm<1,4,2,1, 0,0,0><<<dim3(64,4), 256, 0, stream>>>(
        ff, f2t + l*262144, f2_b + l*DV, s_ff, 2048, 256, 1024, 256,
        nullptr, nullptr, nullptr);
    if(it < 3)
      ln_res_kernel<<<512, 256, 0, stream>>>(s_ff, h1, h, hb, ln2_g + l*DV, ln2_b + l*DV);
  }
  final_pool_kernel<<<64, 256, 0, stream>>>(s_ff, h1, ln2_g + DV, ln2_b + DV, on_g, on_b, part);
  head_kernel<<<250, 128, 0, stream>>>(part, head_w, head_b, out);
}